// Round 1
// baseline (1969.882 us; speedup 1.0000x reference)
//
#include <hip/hip_runtime.h>
#include <hip/hip_bf16.h>

// Problem constants (match reference)
#define NN     20000
#define ERAW   320000
#define ETOT   (ERAW + NN)   // 340000 with self loops
#define F_IN   50
#define HID    64
#define HEADS  8
#define WIDTH  512           // HID*HEADS
#define NCLS   121

// ---------------- GEMM: C[N,M] = A[N,K] @ B[K,M], fp32, row-major ----------
#define BM 64
#define BN 64
#define BK 16
__global__ __launch_bounds__(256) void gemm_f32(
    const float* __restrict__ A, const float* __restrict__ B,
    float* __restrict__ C, int N, int K, int M) {
  __shared__ float As[BK][BM + 1];
  __shared__ float Bs[BK][BN + 1];
  const int tid = threadIdx.x;
  const int tx = tid & 15, ty = tid >> 4;
  const int row0 = blockIdx.y * BM, col0 = blockIdx.x * BN;
  float acc[4][4] = {};
  for (int k0 = 0; k0 < K; k0 += BK) {
    // A tile: 64 rows x 16 k
    #pragma unroll
    for (int i = 0; i < 4; ++i) {
      int r = (tid >> 4) + i * 16;   // 0..63
      int kk = tid & 15;
      int gr = row0 + r, gk = k0 + kk;
      float v = 0.f;
      if (gr < N && gk < K) v = A[gr * K + gk];
      As[kk][r] = v;
    }
    // B tile: 16 k x 64 cols
    #pragma unroll
    for (int i = 0; i < 4; ++i) {
      int r = (tid >> 6) + i * 4;    // 0..15
      int c = tid & 63;
      int gk = k0 + r, gc = col0 + c;
      float v = 0.f;
      if (gk < K && gc < M) v = B[gk * M + gc];
      Bs[r][c] = v;
    }
    __syncthreads();
    #pragma unroll
    for (int kk = 0; kk < BK; ++kk) {
      float a[4], b[4];
      #pragma unroll
      for (int i = 0; i < 4; ++i) a[i] = As[kk][ty * 4 + i];
      #pragma unroll
      for (int j = 0; j < 4; ++j) b[j] = Bs[kk][tx * 4 + j];
      #pragma unroll
      for (int i = 0; i < 4; ++i)
        #pragma unroll
        for (int j = 0; j < 4; ++j) acc[i][j] += a[i] * b[j];
    }
    __syncthreads();
  }
  #pragma unroll
  for (int i = 0; i < 4; ++i) {
    int gr = row0 + ty * 4 + i;
    if (gr >= N) continue;
    #pragma unroll
    for (int j = 0; j < 4; ++j) {
      int gc = col0 + tx * 4 + j;
      if (gc < M) C[gr * M + gc] = acc[i][j];
    }
  }
}

// ---------------- per-node attention logits: al = sum_c h[n,h,c]*a[h,c] ----
__global__ __launch_bounds__(256) void compute_al(
    const float* __restrict__ h, const float* __restrict__ a_src,
    const float* __restrict__ a_dst, float* __restrict__ al_s,
    float* __restrict__ al_d, int Nn, int H, int C) {
  int wave = (blockIdx.x * blockDim.x + threadIdx.x) >> 6;
  int lane = threadIdx.x & 63;
  if (wave >= Nn) return;
  const float* hr = h + (size_t)wave * H * C;
  for (int hd = 0; hd < H; ++hd) {
    float ss = 0.f, sd = 0.f;
    for (int c = lane; c < C; c += 64) {
      float v = hr[hd * C + c];
      ss += v * a_src[hd * C + c];
      sd += v * a_dst[hd * C + c];
    }
    #pragma unroll
    for (int o = 32; o; o >>= 1) {
      ss += __shfl_xor(ss, o);
      sd += __shfl_xor(sd, o);
    }
    if (lane == 0) {
      al_s[wave * H + hd] = ss;
      al_d[wave * H + hd] = sd;
    }
  }
}

// ---------------- ordered-uint float max trick ------------------------------
__device__ __forceinline__ unsigned f2ord(float f) {
  unsigned u = __float_as_uint(f);
  return (u & 0x80000000u) ? ~u : (u | 0x80000000u);
}
__device__ __forceinline__ float ord2f(unsigned o) {
  return (o & 0x80000000u) ? __uint_as_float(o ^ 0x80000000u)
                           : __uint_as_float(~o);
}

__device__ __forceinline__ void edge_sd(int e, const int* esrc, const int* edst,
                                        int Eraw, int& s, int& d) {
  if (e < Eraw) { s = esrc[e]; d = edst[e]; }
  else          { s = e - Eraw; d = e - Eraw; }
}

// ---------------- edge pass A: leaky_relu score + segment max ---------------
__global__ __launch_bounds__(256) void edge_score_max(
    const int* __restrict__ esrc, const int* __restrict__ edst,
    const float* __restrict__ al_s, const float* __restrict__ al_d,
    float* __restrict__ scores, unsigned* __restrict__ m_ord,
    int Etot, int Eraw, int H) {
  int idx = blockIdx.x * blockDim.x + threadIdx.x;
  if (idx >= Etot * H) return;
  int e = idx / H, hd = idx - e * H;
  int s, d; edge_sd(e, esrc, edst, Eraw, s, d);
  float v = al_s[s * H + hd] + al_d[d * H + hd];
  v = (v > 0.f) ? v : 0.2f * v;           // leaky_relu(., 0.2)
  scores[idx] = v;
  atomicMax(&m_ord[d * H + hd], f2ord(v));
}

// ---------------- edge pass B: exp(score - max) + segment sum ---------------
__global__ __launch_bounds__(256) void edge_exp_sum(
    const int* __restrict__ esrc, const int* __restrict__ edst,
    float* __restrict__ scores, const unsigned* __restrict__ m_ord,
    float* __restrict__ z, int Etot, int Eraw, int H) {
  int idx = blockIdx.x * blockDim.x + threadIdx.x;
  if (idx >= Etot * H) return;
  int e = idx / H, hd = idx - e * H;
  int s, d; edge_sd(e, esrc, edst, Eraw, s, d);
  float mv = ord2f(m_ord[d * H + hd]);
  float ex = __expf(scores[idx] - mv);
  scores[idx] = ex;
  atomicAdd(&z[d * H + hd], ex);
}

// ---------------- normalize: alpha = ex / (z[dst] + 1e-16) ------------------
__global__ __launch_bounds__(256) void edge_normalize(
    const int* __restrict__ esrc, const int* __restrict__ edst,
    float* __restrict__ scores, const float* __restrict__ z,
    int Etot, int Eraw, int H) {
  int idx = blockIdx.x * blockDim.x + threadIdx.x;
  if (idx >= Etot * H) return;
  int e = idx / H, hd = idx - e * H;
  int s, d; edge_sd(e, esrc, edst, Eraw, s, d);
  scores[idx] = scores[idx] / (z[d * H + hd] + 1e-16f);
}

// ---------------- aggregation: out[dst] += h[src] * alpha -------------------
__global__ __launch_bounds__(256) void aggregate(
    const int* __restrict__ esrc, const int* __restrict__ edst,
    const float* __restrict__ alpha, const float* __restrict__ h,
    float* __restrict__ out, int Etot, int Eraw, int H, int C) {
  int wave = (blockIdx.x * blockDim.x + threadIdx.x) >> 6;
  int lane = threadIdx.x & 63;
  if (wave >= Etot) return;
  int e = wave;
  int s, d; edge_sd(e, esrc, edst, Eraw, s, d);
  const int HC = H * C;
  const float* hs = h + (size_t)s * HC;
  float* od = out + (size_t)d * HC;
  for (int i = lane; i < HC; i += 64) {
    int hd = (H == 1) ? 0 : (i / C);
    float a = alpha[e * H + hd];
    atomicAdd(&od[i], hs[i] * a);
  }
}

// ---------------- epilogues -------------------------------------------------
__global__ __launch_bounds__(256) void bias_elu_inplace(
    float* __restrict__ x, const float* __restrict__ b, int total, int M) {
  int idx = blockIdx.x * blockDim.x + threadIdx.x;
  if (idx >= total) return;
  float v = x[idx] + b[idx % M];
  x[idx] = (v > 0.f) ? v : expm1f(v);
}
__global__ __launch_bounds__(256) void bias_inplace(
    float* __restrict__ x, const float* __restrict__ b, int total, int M) {
  int idx = blockIdx.x * blockDim.x + threadIdx.x;
  if (idx >= total) return;
  x[idx] = x[idx] + b[idx % M];
}

// ---------------- host-side layer driver ------------------------------------
static void run_gat_layer(const float* x_in, int K, const float* W,
                          const float* a_s, const float* a_d, const float* b,
                          int H, int C, float* h_buf, float* agg_buf,
                          bool do_elu,
                          const int* esrc, const int* edst,
                          float* scores, float* al_s, float* al_d,
                          unsigned* m_ord, float* z, hipStream_t stream) {
  const int M = H * C;
  // 1. GEMM h = x @ W
  dim3 ggrid((M + BN - 1) / BN, (NN + BM - 1) / BM);
  gemm_f32<<<ggrid, 256, 0, stream>>>(x_in, W, h_buf, NN, K, M);
  // 2. attention logits
  compute_al<<<(NN + 3) / 4, 256, 0, stream>>>(h_buf, a_s, a_d, al_s, al_d,
                                               NN, H, C);
  // 3. zero scratch
  hipMemsetAsync(m_ord, 0, (size_t)NN * H * sizeof(unsigned), stream);
  hipMemsetAsync(z, 0, (size_t)NN * H * sizeof(float), stream);
  hipMemsetAsync(agg_buf, 0, (size_t)NN * M * sizeof(float), stream);
  // 4. edge passes
  int tot = ETOT * H;
  int blk = (tot + 255) / 256;
  edge_score_max<<<blk, 256, 0, stream>>>(esrc, edst, al_s, al_d, scores,
                                          m_ord, ETOT, ERAW, H);
  edge_exp_sum<<<blk, 256, 0, stream>>>(esrc, edst, scores, m_ord, z,
                                        ETOT, ERAW, H);
  edge_normalize<<<blk, 256, 0, stream>>>(esrc, edst, scores, z,
                                          ETOT, ERAW, H);
  // 5. aggregate (wave per edge)
  aggregate<<<(ETOT + 3) / 4, 256, 0, stream>>>(esrc, edst, scores, h_buf,
                                                agg_buf, ETOT, ERAW, H, C);
  // 6. epilogue
  int total = NN * M;
  if (do_elu)
    bias_elu_inplace<<<(total + 255) / 256, 256, 0, stream>>>(agg_buf, b,
                                                              total, M);
  else
    bias_inplace<<<(total + 255) / 256, 256, 0, stream>>>(agg_buf, b,
                                                          total, M);
}

extern "C" void kernel_launch(void* const* d_in, const int* in_sizes, int n_in,
                              void* d_out, int out_size, void* d_ws,
                              size_t ws_size, hipStream_t stream) {
  const float* x      = (const float*)d_in[0];
  const int*   ei     = (const int*)d_in[1];
  const float* W1     = (const float*)d_in[2];
  const float* a1_src = (const float*)d_in[3];
  const float* a1_dst = (const float*)d_in[4];
  const float* b1     = (const float*)d_in[5];
  const float* W2     = (const float*)d_in[6];
  const float* a2_src = (const float*)d_in[7];
  const float* a2_dst = (const float*)d_in[8];
  const float* b2     = (const float*)d_in[9];
  const float* W3     = (const float*)d_in[10];
  const float* a3_src = (const float*)d_in[11];
  const float* a3_dst = (const float*)d_in[12];
  const float* b3     = (const float*)d_in[13];
  float* out = (float*)d_out;

  const int* esrc = ei;
  const int* edst = ei + ERAW;

  // Workspace carve-up (floats)
  float* bufA   = (float*)d_ws;                       // 20000*512 h buffer
  float* bufB   = bufA + (size_t)NN * WIDTH;          // 20000*512 agg / x_next
  float* scores = bufB + (size_t)NN * WIDTH;          // 340000*8
  float* al_s   = scores + (size_t)ETOT * HEADS;
  float* al_d   = al_s + (size_t)NN * HEADS;
  unsigned* m_ord = (unsigned*)(al_d + (size_t)NN * HEADS);
  float* z      = (float*)m_ord + (size_t)NN * HEADS;

  // Layer 1: x[20000,50] -> h1(bufA)[20000,512]; agg+elu -> bufB
  run_gat_layer(x, F_IN, W1, a1_src, a1_dst, b1, HEADS, HID, bufA, bufB,
                true, esrc, edst, scores, al_s, al_d, m_ord, z, stream);
  // Layer 2: bufB -> h2(bufA); agg+elu -> bufB (bufB free after GEMM? no —
  // GEMM reads bufB fully before we need to overwrite. The memset of agg_buf
  // happens after the GEMM launch in run_gat_layer, and stream ordering makes
  // the GEMM finish first, so in-place input->agg reuse is safe.)
  run_gat_layer(bufB, WIDTH, W2, a2_src, a2_dst, b2, 1, WIDTH, bufA, bufB,
                true, esrc, edst, scores, al_s, al_d, m_ord, z, stream);
  // Layer 3: bufB -> h3(bufA)[20000,121]; agg -> d_out; + b3 (mean over 1
  // head is identity)
  hipMemsetAsync(out, 0, (size_t)NN * NCLS * sizeof(float), stream);
  {
    const int H = 1, C = NCLS, M = NCLS;
    dim3 ggrid((M + BN - 1) / BN, (NN + BM - 1) / BM);
    gemm_f32<<<ggrid, 256, 0, stream>>>(bufB, W3, bufA, NN, WIDTH, M);
    compute_al<<<(NN + 3) / 4, 256, 0, stream>>>(bufA, a3_src, a3_dst, al_s,
                                                 al_d, NN, H, C);
    hipMemsetAsync(m_ord, 0, (size_t)NN * H * sizeof(unsigned), stream);
    hipMemsetAsync(z, 0, (size_t)NN * H * sizeof(float), stream);
    int tot = ETOT * H;
    int blk = (tot + 255) / 256;
    edge_score_max<<<blk, 256, 0, stream>>>(esrc, edst, al_s, al_d, scores,
                                            m_ord, ETOT, ERAW, H);
    edge_exp_sum<<<blk, 256, 0, stream>>>(esrc, edst, scores, m_ord, z,
                                          ETOT, ERAW, H);
    edge_normalize<<<blk, 256, 0, stream>>>(esrc, edst, scores, z,
                                            ETOT, ERAW, H);
    aggregate<<<(ETOT + 3) / 4, 256, 0, stream>>>(esrc, edst, scores, bufA,
                                                  out, ETOT, ERAW, H, C);
    int total = NN * M;
    bias_inplace<<<(total + 255) / 256, 256, 0, stream>>>(out, b3, total, M);
  }
}

// Round 3
// 995.648 us; speedup vs baseline: 1.9785x; 1.9785x over previous
//
#include <hip/hip_runtime.h>
#include <hip/hip_bf16.h>

// Problem constants (match reference)
#define NN     20000
#define ERAW   320000
#define ETOT   (ERAW + NN)   // 340000 with self loops
#define F_IN   50
#define HID    64
#define HEADS  8
#define WIDTH  512           // HID*HEADS
#define NCLS   121

// ---------------- GEMM: C[N,M] = A[N,K] @ B[K,M], fp32, row-major ----------
#define BM 64
#define BN 64
#define BK 16
__global__ __launch_bounds__(256) void gemm_f32(
    const float* __restrict__ A, const float* __restrict__ B,
    float* __restrict__ C, int N, int K, int M) {
  __shared__ float As[BK][BM + 1];
  __shared__ float Bs[BK][BN + 1];
  const int tid = threadIdx.x;
  const int tx = tid & 15, ty = tid >> 4;
  const int row0 = blockIdx.y * BM, col0 = blockIdx.x * BN;
  float acc[4][4] = {};
  for (int k0 = 0; k0 < K; k0 += BK) {
    #pragma unroll
    for (int i = 0; i < 4; ++i) {
      int r = (tid >> 4) + i * 16;
      int kk = tid & 15;
      int gr = row0 + r, gk = k0 + kk;
      float v = 0.f;
      if (gr < N && gk < K) v = A[gr * K + gk];
      As[kk][r] = v;
    }
    #pragma unroll
    for (int i = 0; i < 4; ++i) {
      int r = (tid >> 6) + i * 4;
      int c = tid & 63;
      int gk = k0 + r, gc = col0 + c;
      float v = 0.f;
      if (gk < K && gc < M) v = B[gk * M + gc];
      Bs[r][c] = v;
    }
    __syncthreads();
    #pragma unroll
    for (int kk = 0; kk < BK; ++kk) {
      float a[4], b[4];
      #pragma unroll
      for (int i = 0; i < 4; ++i) a[i] = As[kk][ty * 4 + i];
      #pragma unroll
      for (int j = 0; j < 4; ++j) b[j] = Bs[kk][tx * 4 + j];
      #pragma unroll
      for (int i = 0; i < 4; ++i)
        #pragma unroll
        for (int j = 0; j < 4; ++j) acc[i][j] += a[i] * b[j];
    }
    __syncthreads();
  }
  #pragma unroll
  for (int i = 0; i < 4; ++i) {
    int gr = row0 + ty * 4 + i;
    if (gr >= N) continue;
    #pragma unroll
    for (int j = 0; j < 4; ++j) {
      int gc = col0 + tx * 4 + j;
      if (gc < M) C[gr * M + gc] = acc[i][j];
    }
  }
}

// ---------------- per-node attention logits: al = sum_c h[n,h,c]*a[h,c] ----
__global__ __launch_bounds__(256) void compute_al(
    const float* __restrict__ h, const float* __restrict__ a_src,
    const float* __restrict__ a_dst, float* __restrict__ al_s,
    float* __restrict__ al_d, int Nn, int H, int C) {
  int wave = (blockIdx.x * blockDim.x + threadIdx.x) >> 6;
  int lane = threadIdx.x & 63;
  if (wave >= Nn) return;
  const float* hr = h + (size_t)wave * H * C;
  for (int hd = 0; hd < H; ++hd) {
    float ss = 0.f, sd = 0.f;
    for (int c = lane; c < C; c += 64) {
      float v = hr[hd * C + c];
      ss += v * a_src[hd * C + c];
      sd += v * a_dst[hd * C + c];
    }
    #pragma unroll
    for (int o = 32; o; o >>= 1) {
      ss += __shfl_xor(ss, o);
      sd += __shfl_xor(sd, o);
    }
    if (lane == 0) {
      al_s[wave * H + hd] = ss;
      al_d[wave * H + hd] = sd;
    }
  }
}

// ---------------- ordered-uint float max trick ------------------------------
__device__ __forceinline__ unsigned f2ord(float f) {
  unsigned u = __float_as_uint(f);
  return (u & 0x80000000u) ? ~u : (u | 0x80000000u);
}
__device__ __forceinline__ float ord2f(unsigned o) {
  return (o & 0x80000000u) ? __uint_as_float(o ^ 0x80000000u)
                           : __uint_as_float(~o);
}

__device__ __forceinline__ void edge_sd(int e, const int* esrc, const int* edst,
                                        int Eraw, int& s, int& d) {
  if (e < Eraw) { s = esrc[e]; d = edst[e]; }
  else          { s = e - Eraw; d = e - Eraw; }
}

// ---------------- edge pass A: leaky_relu score + segment max ---------------
__global__ __launch_bounds__(256) void edge_score_max(
    const int* __restrict__ esrc, const int* __restrict__ edst,
    const float* __restrict__ al_s, const float* __restrict__ al_d,
    float* __restrict__ scores, unsigned* __restrict__ m_ord,
    int Etot, int Eraw, int H) {
  int idx = blockIdx.x * blockDim.x + threadIdx.x;
  if (idx >= Etot * H) return;
  int e = idx / H, hd = idx - e * H;
  int s, d; edge_sd(e, esrc, edst, Eraw, s, d);
  float v = al_s[s * H + hd] + al_d[d * H + hd];
  v = (v > 0.f) ? v : 0.2f * v;           // leaky_relu(., 0.2)
  scores[idx] = v;
  atomicMax(&m_ord[d * H + hd], f2ord(v));
}

// ---------------- edge pass B: exp(score - max) + segment sum ---------------
__global__ __launch_bounds__(256) void edge_exp_sum(
    const int* __restrict__ esrc, const int* __restrict__ edst,
    float* __restrict__ scores, const unsigned* __restrict__ m_ord,
    float* __restrict__ z, int Etot, int Eraw, int H) {
  int idx = blockIdx.x * blockDim.x + threadIdx.x;
  if (idx >= Etot * H) return;
  int e = idx / H, hd = idx - e * H;
  int s, d; edge_sd(e, esrc, edst, Eraw, s, d);
  float mv = ord2f(m_ord[d * H + hd]);
  float ex = __expf(scores[idx] - mv);
  scores[idx] = ex;      // scores now holds UNNORMALIZED exp
  atomicAdd(&z[d * H + hd], ex);
}

// ---------------- CSR build (once; shared by all layers) --------------------
__global__ __launch_bounds__(256) void count_deg(
    const int* __restrict__ edst, int* __restrict__ deg) {
  int e = blockIdx.x * blockDim.x + threadIdx.x;
  if (e >= ETOT) return;
  int d = (e < ERAW) ? edst[e] : (e - ERAW);
  atomicAdd(&deg[d], 1);
}

// single-block exclusive scan over NN entries -> rowptr[NN+1]
__global__ __launch_bounds__(256) void scan_deg(
    const int* __restrict__ deg, int* __restrict__ rowptr) {
  __shared__ int part[256];
  const int t = threadIdx.x;
  const int CHUNK = (NN + 255) / 256;  // 79
  int lo = t * CHUNK, hi = min(lo + CHUNK, NN);
  int s = 0;
  for (int i = lo; i < hi; ++i) s += deg[i];
  part[t] = s;
  __syncthreads();
  for (int off = 1; off < 256; off <<= 1) {
    int v = (t >= off) ? part[t - off] : 0;
    __syncthreads();
    part[t] += v;
    __syncthreads();
  }
  int base = (t == 0) ? 0 : part[t - 1];
  for (int i = lo; i < hi; ++i) {
    rowptr[i] = base;
    base += deg[i];
  }
  if (t == 255) rowptr[NN] = part[255];
}

__global__ __launch_bounds__(256) void scatter_csr(
    const int* __restrict__ esrc, const int* __restrict__ edst,
    const int* __restrict__ rowptr, int* __restrict__ cnt,
    int* __restrict__ ceid, int* __restrict__ csrc) {
  int e = blockIdx.x * blockDim.x + threadIdx.x;
  if (e >= ETOT) return;
  int s, d;
  if (e < ERAW) { s = esrc[e]; d = edst[e]; }
  else          { s = e - ERAW; d = e - ERAW; }
  int pos = rowptr[d] + atomicAdd(&cnt[d], 1);
  ceid[pos] = e;
  csrc[pos] = s;
}

// ---- pull aggregation: one wave per dst node, no atomics, fused epilogue ---
// out[d, :] = (1/(z[d]+eps)) * sum_e ex[e] * h[src_e, :] + bias  (then ELU)
template <int H, int C, bool ELU>
__global__ __launch_bounds__(256) void pull_agg(
    const int* __restrict__ rowptr, const int* __restrict__ ceid,
    const int* __restrict__ csrc, const float* __restrict__ ex,
    const float* __restrict__ z, const float* __restrict__ h,
    const float* __restrict__ bias, float* __restrict__ out) {
  constexpr int M = H * C;
  constexpr int EPL = (M + 63) / 64;  // elements per lane
  const int w = threadIdx.x >> 6;
  const int lane = threadIdx.x & 63;
  const int d = blockIdx.x * 4 + w;
  if (d >= NN) return;
  const int r0 = rowptr[d], r1 = rowptr[d + 1];
  const int base = lane * EPL;
  const int myh = (H == 1) ? 0 : (base / C);  // lane's 8 elems lie in one head
  const float iz = 1.0f / (z[d * H + myh] + 1e-16f);

  float acc[EPL];
  #pragma unroll
  for (int j = 0; j < EPL; ++j) acc[j] = 0.f;
  for (int p = r0; p < r1; ++p) {
    int eid = ceid[p];
    int s = csrc[p];
    float a = ex[(size_t)eid * H + myh];
    const float* hr = h + (size_t)s * M + base;
    #pragma unroll
    for (int j = 0; j < EPL; ++j) {
      if ((M % 64 == 0) || (base + j < M)) acc[j] += hr[j] * a;
    }
  }

  float* od = out + (size_t)d * M + base;
  #pragma unroll
  for (int j = 0; j < EPL; ++j) {
    if ((M % 64 == 0) || (base + j < M)) {
      float v = acc[j] * iz + bias[base + j];
      if (ELU) v = (v > 0.f) ? v : expm1f(v);
      od[j] = v;
    }
  }
}

extern "C" void kernel_launch(void* const* d_in, const int* in_sizes, int n_in,
                              void* d_out, int out_size, void* d_ws,
                              size_t ws_size, hipStream_t stream) {
  const float* x      = (const float*)d_in[0];
  const int*   ei     = (const int*)d_in[1];
  const float* W1     = (const float*)d_in[2];
  const float* a1_src = (const float*)d_in[3];
  const float* a1_dst = (const float*)d_in[4];
  const float* b1     = (const float*)d_in[5];
  const float* W2     = (const float*)d_in[6];
  const float* a2_src = (const float*)d_in[7];
  const float* a2_dst = (const float*)d_in[8];
  const float* b2     = (const float*)d_in[9];
  const float* W3     = (const float*)d_in[10];
  const float* a3_src = (const float*)d_in[11];
  const float* a3_dst = (const float*)d_in[12];
  const float* b3     = (const float*)d_in[13];
  float* out = (float*)d_out;

  const int* esrc = ei;
  const int* edst = ei + ERAW;

  // Workspace carve-up (floats)
  float* bufA   = (float*)d_ws;                        // 20000*512
  float* bufB   = bufA + (size_t)NN * WIDTH;           // 20000*512
  float* scores = bufB + (size_t)NN * WIDTH;           // 340000*8
  float* al_s   = scores + (size_t)ETOT * HEADS;       // 20000*8
  float* al_d   = al_s + (size_t)NN * HEADS;           // 20000*8
  unsigned* m_ord = (unsigned*)(al_d + (size_t)NN * HEADS);  // 20000*8
  float* z      = (float*)m_ord + (size_t)NN * HEADS;  // 20000*8
  int* deg      = (int*)(z + (size_t)NN * HEADS);      // 20000
  int* rowptr   = deg + NN;                            // 20001 (+3 pad)
  int* cnt      = rowptr + NN + 4;                     // 20000
  int* ceid     = cnt + NN;                            // 340000
  int* csrc     = ceid + ETOT;                         // 340000

  // ---- build CSR by destination (once) ----
  hipMemsetAsync(deg, 0, (size_t)NN * sizeof(int), stream);
  hipMemsetAsync(cnt, 0, (size_t)NN * sizeof(int), stream);
  const int eblk = (ETOT + 255) / 256;
  count_deg<<<eblk, 256, 0, stream>>>(edst, deg);
  scan_deg<<<1, 256, 0, stream>>>(deg, rowptr);
  scatter_csr<<<eblk, 256, 0, stream>>>(esrc, edst, rowptr, cnt, ceid, csrc);

  const int nwblk = (NN + 3) / 4;  // 1 wave per node, 4 waves per block

  // ---- Layer 1: x[20000,50] @ W1 -> h1(bufA); softmax-agg+ELU -> bufB ----
  {
    const int H = HEADS, C = HID;
    dim3 g((WIDTH + BN - 1) / BN, (NN + BM - 1) / BM);
    gemm_f32<<<g, 256, 0, stream>>>(x, W1, bufA, NN, F_IN, WIDTH);
    compute_al<<<nwblk, 256, 0, stream>>>(bufA, a1_src, a1_dst, al_s, al_d,
                                          NN, H, C);
    hipMemsetAsync(m_ord, 0, (size_t)NN * H * sizeof(unsigned), stream);
    hipMemsetAsync(z, 0, (size_t)NN * H * sizeof(float), stream);
    int tot = ETOT * H, blk = (tot + 255) / 256;
    edge_score_max<<<blk, 256, 0, stream>>>(esrc, edst, al_s, al_d, scores,
                                            m_ord, ETOT, ERAW, H);
    edge_exp_sum<<<blk, 256, 0, stream>>>(esrc, edst, scores, m_ord, z,
                                          ETOT, ERAW, H);
    pull_agg<HEADS, HID, true><<<nwblk, 256, 0, stream>>>(
        rowptr, ceid, csrc, scores, z, bufA, b1, bufB);
  }
  // ---- Layer 2: bufB @ W2 -> h2(bufA); softmax-agg+ELU -> bufB ----
  {
    const int H = 1, C = WIDTH;
    dim3 g((WIDTH + BN - 1) / BN, (NN + BM - 1) / BM);
    gemm_f32<<<g, 256, 0, stream>>>(bufB, W2, bufA, NN, WIDTH, WIDTH);
    compute_al<<<nwblk, 256, 0, stream>>>(bufA, a2_src, a2_dst, al_s, al_d,
                                          NN, H, C);
    hipMemsetAsync(m_ord, 0, (size_t)NN * H * sizeof(unsigned), stream);
    hipMemsetAsync(z, 0, (size_t)NN * H * sizeof(float), stream);
    int tot = ETOT * H, blk = (tot + 255) / 256;
    edge_score_max<<<blk, 256, 0, stream>>>(esrc, edst, al_s, al_d, scores,
                                            m_ord, ETOT, ERAW, H);
    edge_exp_sum<<<blk, 256, 0, stream>>>(esrc, edst, scores, m_ord, z,
                                          ETOT, ERAW, H);
    pull_agg<1, WIDTH, true><<<nwblk, 256, 0, stream>>>(
        rowptr, ceid, csrc, scores, z, bufA, b2, bufB);
  }
  // ---- Layer 3: bufB @ W3 -> h3(bufA); softmax-agg -> out (no ELU) ----
  {
    const int H = 1, C = NCLS;
    dim3 g((NCLS + BN - 1) / BN, (NN + BM - 1) / BM);
    gemm_f32<<<g, 256, 0, stream>>>(bufB, W3, bufA, NN, WIDTH, NCLS);
    compute_al<<<nwblk, 256, 0, stream>>>(bufA, a3_src, a3_dst, al_s, al_d,
                                          NN, H, C);
    hipMemsetAsync(m_ord, 0, (size_t)NN * H * sizeof(unsigned), stream);
    hipMemsetAsync(z, 0, (size_t)NN * H * sizeof(float), stream);
    int tot = ETOT * H, blk = (tot + 255) / 256;
    edge_score_max<<<blk, 256, 0, stream>>>(esrc, edst, al_s, al_d, scores,
                                            m_ord, ETOT, ERAW, H);
    edge_exp_sum<<<blk, 256, 0, stream>>>(esrc, edst, scores, m_ord, z,
                                          ETOT, ERAW, H);
    pull_agg<1, NCLS, false><<<nwblk, 256, 0, stream>>>(
        rowptr, ceid, csrc, scores, z, bufA, b3, out);
  }
}

// Round 4
// 747.472 us; speedup vs baseline: 2.6354x; 1.3320x over previous
//
#include <hip/hip_runtime.h>
#include <hip/hip_bf16.h>

// Problem constants (match reference)
#define NN     20000
#define ERAW   320000
#define ETOT   (ERAW + NN)   // 340000 with self loops
#define F_IN   50
#define HID    64
#define HEADS  8
#define WIDTH  512           // HID*HEADS
#define NCLS   121
#define NCLS_P 128           // padded cols for layer-3 MFMA GEMM

typedef __attribute__((ext_vector_type(8))) __bf16 bf16x8;
typedef __attribute__((ext_vector_type(4))) float floatx4;

// ---------------- fp32 -> bf16 split helpers --------------------------------
__device__ __forceinline__ unsigned short f32_to_bf16_rn(float f) {
  unsigned u = __float_as_uint(f);
  unsigned r = u + 0x7fffu + ((u >> 16) & 1u);
  return (unsigned short)(r >> 16);
}
__device__ __forceinline__ void split_one(float f, unsigned short& h,
                                          unsigned short& l) {
  h = f32_to_bf16_rn(f);
  float fh = __uint_as_float(((unsigned)h) << 16);
  l = f32_to_bf16_rn(f - fh);
}

// split fp32 array into hi/lo bf16 (vectorized x4)
__global__ __launch_bounds__(256) void split_hi_lo4(
    const float4* __restrict__ A, ushort4* __restrict__ hi,
    ushort4* __restrict__ lo, int total4) {
  int i = blockIdx.x * blockDim.x + threadIdx.x;
  if (i >= total4) return;
  float4 f = A[i];
  ushort4 h, l;
  split_one(f.x, h.x, l.x);
  split_one(f.y, h.y, l.y);
  split_one(f.z, h.z, l.z);
  split_one(f.w, h.w, l.w);
  hi[i] = h;
  lo[i] = l;
}

// W [K][M] fp32 -> Bt hi/lo [Mp][K] bf16 ushort (rows m>=M zero-padded)
__global__ __launch_bounds__(256) void transpose_split(
    const float* __restrict__ W, unsigned short* __restrict__ thi,
    unsigned short* __restrict__ tlo, int K, int M, int Mp) {
  __shared__ float t[32][33];
  int k0 = blockIdx.x * 32, m0 = blockIdx.y * 32;
  int tx = threadIdx.x & 31, ty = threadIdx.x >> 5;  // 32 x 8
  #pragma unroll
  for (int r = 0; r < 4; ++r) {
    int k = k0 + ty + r * 8, m = m0 + tx;
    float v = 0.f;
    if (k < K && m < M) v = W[(size_t)k * M + m];
    t[ty + r * 8][tx] = v;
  }
  __syncthreads();
  #pragma unroll
  for (int r = 0; r < 4; ++r) {
    int m = m0 + ty + r * 8, k = k0 + tx;
    if (m < Mp && k < K) {
      unsigned short h, l;
      split_one(t[tx][ty + r * 8], h, l);
      thi[(size_t)m * K + k] = h;
      tlo[(size_t)m * K + k] = l;
    }
  }
}

// ---- split-bf16 MFMA GEMM: C[N,M] = A[N,K] @ B[K,M] (B given as Bt[Mp][K]) -
// 3-term: AhiBhi + AhiBlo + AloBhi; fp32 accumulate. K % 32 == 0.
// Block tile 128x128, 256 threads (4 waves, 2x2 of 64x64 wave tiles).
__global__ __launch_bounds__(256) void gemm_mfma_split(
    const unsigned short* __restrict__ Ahi, const unsigned short* __restrict__ Alo,
    const unsigned short* __restrict__ Bthi, const unsigned short* __restrict__ Btlo,
    float* __restrict__ C, int N, int K, int M) {
  // LDS fragment-ordered: [kg(4)][row(128)][8 bf16] per region
  __shared__ unsigned short sAhi[4096], sAlo[4096], sBhi[4096], sBlo[4096];
  const int tid = threadIdx.x;
  const int wave = tid >> 6, lane = tid & 63;
  const int wr = wave >> 1, wc = wave & 1;
  const int r0 = blockIdx.y * 128;
  const int c0 = blockIdx.x * 128;
  const int lkg = lane >> 4;    // 0..3 (k-group of fragment)
  const int lmn = lane & 15;    // m/n within 16-tile

  // staging assignment: thread -> (kg, row) and (kg, row+64)
  const int skg = tid & 3;
  const int srow = tid >> 2;    // 0..63
  int ra0 = r0 + srow;        if (ra0 > NN - 1) ra0 = NN - 1;
  int ra1 = r0 + srow + 64;   if (ra1 > NN - 1) ra1 = NN - 1;
  const unsigned short* gAhi0 = Ahi + (size_t)ra0 * K + skg * 8;
  const unsigned short* gAhi1 = Ahi + (size_t)ra1 * K + skg * 8;
  const unsigned short* gAlo0 = Alo + (size_t)ra0 * K + skg * 8;
  const unsigned short* gAlo1 = Alo + (size_t)ra1 * K + skg * 8;
  const unsigned short* gBhi0 = Bthi + (size_t)(c0 + srow) * K + skg * 8;
  const unsigned short* gBhi1 = Bthi + (size_t)(c0 + srow + 64) * K + skg * 8;
  const unsigned short* gBlo0 = Btlo + (size_t)(c0 + srow) * K + skg * 8;
  const unsigned short* gBlo1 = Btlo + (size_t)(c0 + srow + 64) * K + skg * 8;

  floatx4 acc[4][4] = {};

  uint4 a0, a1, a2, a3, b0, b1, b2, b3;
  auto gload = [&](int kk) {
    a0 = *(const uint4*)(gAhi0 + kk);
    a1 = *(const uint4*)(gAhi1 + kk);
    a2 = *(const uint4*)(gAlo0 + kk);
    a3 = *(const uint4*)(gAlo1 + kk);
    b0 = *(const uint4*)(gBhi0 + kk);
    b1 = *(const uint4*)(gBhi1 + kk);
    b2 = *(const uint4*)(gBlo0 + kk);
    b3 = *(const uint4*)(gBlo1 + kk);
  };
  gload(0);

  const int w0 = (skg * 128 + srow) * 8;
  const int w1 = (skg * 128 + srow + 64) * 8;

  for (int k0 = 0; k0 < K; k0 += 32) {
    __syncthreads();  // prior iteration's LDS reads complete
    *(uint4*)(sAhi + w0) = a0;
    *(uint4*)(sAhi + w1) = a1;
    *(uint4*)(sAlo + w0) = a2;
    *(uint4*)(sAlo + w1) = a3;
    *(uint4*)(sBhi + w0) = b0;
    *(uint4*)(sBhi + w1) = b1;
    *(uint4*)(sBlo + w0) = b2;
    *(uint4*)(sBlo + w1) = b3;
    __syncthreads();
    if (k0 + 32 < K) gload(k0 + 32);  // prefetch overlaps with MFMA below

    bf16x8 fAhi[4], fAlo[4], fBhi[4], fBlo[4];
    #pragma unroll
    for (int mi = 0; mi < 4; ++mi) {
      int m = wr * 64 + mi * 16 + lmn;
      fAhi[mi] = *(const bf16x8*)(sAhi + (lkg * 128 + m) * 8);
      fAlo[mi] = *(const bf16x8*)(sAlo + (lkg * 128 + m) * 8);
    }
    #pragma unroll
    for (int ni = 0; ni < 4; ++ni) {
      int n = wc * 64 + ni * 16 + lmn;
      fBhi[ni] = *(const bf16x8*)(sBhi + (lkg * 128 + n) * 8);
      fBlo[ni] = *(const bf16x8*)(sBlo + (lkg * 128 + n) * 8);
    }
    #pragma unroll
    for (int mi = 0; mi < 4; ++mi)
      #pragma unroll
      for (int ni = 0; ni < 4; ++ni) {
        acc[mi][ni] = __builtin_amdgcn_mfma_f32_16x16x32_bf16(
            fAhi[mi], fBhi[ni], acc[mi][ni], 0, 0, 0);
        acc[mi][ni] = __builtin_amdgcn_mfma_f32_16x16x32_bf16(
            fAhi[mi], fBlo[ni], acc[mi][ni], 0, 0, 0);
        acc[mi][ni] = __builtin_amdgcn_mfma_f32_16x16x32_bf16(
            fAlo[mi], fBhi[ni], acc[mi][ni], 0, 0, 0);
      }
  }

  // epilogue: C/D layout col=lane&15, row=(lane>>4)*4+reg
  #pragma unroll
  for (int mi = 0; mi < 4; ++mi) {
    #pragma unroll
    for (int r = 0; r < 4; ++r) {
      int grow = r0 + wr * 64 + mi * 16 + (lane >> 4) * 4 + r;
      if (grow >= N) continue;
      #pragma unroll
      for (int ni = 0; ni < 4; ++ni) {
        int gcol = c0 + wc * 64 + ni * 16 + lmn;
        if (gcol < M) C[(size_t)grow * M + gcol] = acc[mi][ni][r];
      }
    }
  }
}

// ---------------- fp32 GEMM (layer 1 only, K=50) ----------------------------
#define BM 64
#define BN 64
#define BK 16
__global__ __launch_bounds__(256) void gemm_f32(
    const float* __restrict__ A, const float* __restrict__ B,
    float* __restrict__ C, int N, int K, int M) {
  __shared__ float As[BK][BM + 1];
  __shared__ float Bs[BK][BN + 1];
  const int tid = threadIdx.x;
  const int tx = tid & 15, ty = tid >> 4;
  const int row0 = blockIdx.y * BM, col0 = blockIdx.x * BN;
  float acc[4][4] = {};
  for (int k0 = 0; k0 < K; k0 += BK) {
    #pragma unroll
    for (int i = 0; i < 4; ++i) {
      int r = (tid >> 4) + i * 16;
      int kk = tid & 15;
      int gr = row0 + r, gk = k0 + kk;
      float v = 0.f;
      if (gr < N && gk < K) v = A[gr * K + gk];
      As[kk][r] = v;
    }
    #pragma unroll
    for (int i = 0; i < 4; ++i) {
      int r = (tid >> 6) + i * 4;
      int c = tid & 63;
      int gk = k0 + r, gc = col0 + c;
      float v = 0.f;
      if (gk < K && gc < M) v = B[gk * M + gc];
      Bs[r][c] = v;
    }
    __syncthreads();
    #pragma unroll
    for (int kk = 0; kk < BK; ++kk) {
      float a[4], b[4];
      #pragma unroll
      for (int i = 0; i < 4; ++i) a[i] = As[kk][ty * 4 + i];
      #pragma unroll
      for (int j = 0; j < 4; ++j) b[j] = Bs[kk][tx * 4 + j];
      #pragma unroll
      for (int i = 0; i < 4; ++i)
        #pragma unroll
        for (int j = 0; j < 4; ++j) acc[i][j] += a[i] * b[j];
    }
    __syncthreads();
  }
  #pragma unroll
  for (int i = 0; i < 4; ++i) {
    int gr = row0 + ty * 4 + i;
    if (gr >= N) continue;
    #pragma unroll
    for (int j = 0; j < 4; ++j) {
      int gc = col0 + tx * 4 + j;
      if (gc < M) C[gr * M + gc] = acc[i][j];
    }
  }
}

// ---------------- per-node attention logits ---------------------------------
__global__ __launch_bounds__(256) void compute_al(
    const float* __restrict__ h, const float* __restrict__ a_src,
    const float* __restrict__ a_dst, float* __restrict__ al_s,
    float* __restrict__ al_d, int Nn, int H, int C) {
  int wave = (blockIdx.x * blockDim.x + threadIdx.x) >> 6;
  int lane = threadIdx.x & 63;
  if (wave >= Nn) return;
  const float* hr = h + (size_t)wave * H * C;
  for (int hd = 0; hd < H; ++hd) {
    float ss = 0.f, sd = 0.f;
    for (int c = lane; c < C; c += 64) {
      float v = hr[hd * C + c];
      ss += v * a_src[hd * C + c];
      sd += v * a_dst[hd * C + c];
    }
    #pragma unroll
    for (int o = 32; o; o >>= 1) {
      ss += __shfl_xor(ss, o);
      sd += __shfl_xor(sd, o);
    }
    if (lane == 0) {
      al_s[wave * H + hd] = ss;
      al_d[wave * H + hd] = sd;
    }
  }
}

// ---------------- ordered-uint float max trick ------------------------------
__device__ __forceinline__ unsigned f2ord(float f) {
  unsigned u = __float_as_uint(f);
  return (u & 0x80000000u) ? ~u : (u | 0x80000000u);
}
__device__ __forceinline__ float ord2f(unsigned o) {
  return (o & 0x80000000u) ? __uint_as_float(o ^ 0x80000000u)
                           : __uint_as_float(~o);
}

__device__ __forceinline__ void edge_sd(int e, const int* esrc, const int* edst,
                                        int Eraw, int& s, int& d) {
  if (e < Eraw) { s = esrc[e]; d = edst[e]; }
  else          { s = e - Eraw; d = e - Eraw; }
}

// ---------------- edge pass A: leaky_relu score + segment max ---------------
__global__ __launch_bounds__(256) void edge_score_max(
    const int* __restrict__ esrc, const int* __restrict__ edst,
    const float* __restrict__ al_s, const float* __restrict__ al_d,
    float* __restrict__ scores, unsigned* __restrict__ m_ord,
    int Etot, int Eraw, int H) {
  int idx = blockIdx.x * blockDim.x + threadIdx.x;
  if (idx >= Etot * H) return;
  int e = idx / H, hd = idx - e * H;
  int s, d; edge_sd(e, esrc, edst, Eraw, s, d);
  float v = al_s[s * H + hd] + al_d[d * H + hd];
  v = (v > 0.f) ? v : 0.2f * v;
  scores[idx] = v;
  atomicMax(&m_ord[d * H + hd], f2ord(v));
}

// ---------------- edge pass B: exp(score - max) + segment sum ---------------
__global__ __launch_bounds__(256) void edge_exp_sum(
    const int* __restrict__ esrc, const int* __restrict__ edst,
    float* __restrict__ scores, const unsigned* __restrict__ m_ord,
    float* __restrict__ z, int Etot, int Eraw, int H) {
  int idx = blockIdx.x * blockDim.x + threadIdx.x;
  if (idx >= Etot * H) return;
  int e = idx / H, hd = idx - e * H;
  int s, d; edge_sd(e, esrc, edst, Eraw, s, d);
  float mv = ord2f(m_ord[d * H + hd]);
  float ex = __expf(scores[idx] - mv);
  scores[idx] = ex;      // scores now holds UNNORMALIZED exp
  atomicAdd(&z[d * H + hd], ex);
}

// ---------------- CSR build (once; shared by all layers) --------------------
__global__ __launch_bounds__(256) void count_deg(
    const int* __restrict__ edst, int* __restrict__ deg) {
  int e = blockIdx.x * blockDim.x + threadIdx.x;
  if (e >= ETOT) return;
  int d = (e < ERAW) ? edst[e] : (e - ERAW);
  atomicAdd(&deg[d], 1);
}

__global__ __launch_bounds__(256) void scan_deg(
    const int* __restrict__ deg, int* __restrict__ rowptr) {
  __shared__ int part[256];
  const int t = threadIdx.x;
  const int CHUNK = (NN + 255) / 256;
  int lo = t * CHUNK, hi = min(lo + CHUNK, NN);
  int s = 0;
  for (int i = lo; i < hi; ++i) s += deg[i];
  part[t] = s;
  __syncthreads();
  for (int off = 1; off < 256; off <<= 1) {
    int v = (t >= off) ? part[t - off] : 0;
    __syncthreads();
    part[t] += v;
    __syncthreads();
  }
  int base = (t == 0) ? 0 : part[t - 1];
  for (int i = lo; i < hi; ++i) {
    rowptr[i] = base;
    base += deg[i];
  }
  if (t == 255) rowptr[NN] = part[255];
}

__global__ __launch_bounds__(256) void scatter_csr(
    const int* __restrict__ esrc, const int* __restrict__ edst,
    const int* __restrict__ rowptr, int* __restrict__ cnt,
    int* __restrict__ ceid, int* __restrict__ csrc) {
  int e = blockIdx.x * blockDim.x + threadIdx.x;
  if (e >= ETOT) return;
  int s, d;
  if (e < ERAW) { s = esrc[e]; d = edst[e]; }
  else          { s = e - ERAW; d = e - ERAW; }
  int pos = rowptr[d] + atomicAdd(&cnt[d], 1);
  ceid[pos] = e;
  csrc[pos] = s;
}

// ---- pull aggregation: one wave per dst node, no atomics, fused epilogue ---
template <int H, int C, bool ELU>
__global__ __launch_bounds__(256) void pull_agg(
    const int* __restrict__ rowptr, const int* __restrict__ ceid,
    const int* __restrict__ csrc, const float* __restrict__ ex,
    const float* __restrict__ z, const float* __restrict__ h,
    const float* __restrict__ bias, float* __restrict__ out) {
  constexpr int M = H * C;
  constexpr int EPL = (M + 63) / 64;
  const int w = threadIdx.x >> 6;
  const int lane = threadIdx.x & 63;
  const int d = blockIdx.x * 4 + w;
  if (d >= NN) return;
  const int r0 = rowptr[d], r1 = rowptr[d + 1];
  const int base = lane * EPL;
  const int myh = (H == 1) ? 0 : (base / C);
  const float iz = 1.0f / (z[d * H + myh] + 1e-16f);

  float acc[EPL];
  #pragma unroll
  for (int j = 0; j < EPL; ++j) acc[j] = 0.f;
  for (int p = r0; p < r1; ++p) {
    int eid = ceid[p];
    int s = csrc[p];
    float a = ex[(size_t)eid * H + myh];
    const float* hr = h + (size_t)s * M + base;
    #pragma unroll
    for (int j = 0; j < EPL; ++j) {
      if ((M % 64 == 0) || (base + j < M)) acc[j] += hr[j] * a;
    }
  }

  float* od = out + (size_t)d * M + base;
  #pragma unroll
  for (int j = 0; j < EPL; ++j) {
    if ((M % 64 == 0) || (base + j < M)) {
      float v = acc[j] * iz + bias[base + j];
      if (ELU) v = (v > 0.f) ? v : expm1f(v);
      od[j] = v;
    }
  }
}

extern "C" void kernel_launch(void* const* d_in, const int* in_sizes, int n_in,
                              void* d_out, int out_size, void* d_ws,
                              size_t ws_size, hipStream_t stream) {
  const float* x      = (const float*)d_in[0];
  const int*   ei     = (const int*)d_in[1];
  const float* W1     = (const float*)d_in[2];
  const float* a1_src = (const float*)d_in[3];
  const float* a1_dst = (const float*)d_in[4];
  const float* b1     = (const float*)d_in[5];
  const float* W2     = (const float*)d_in[6];
  const float* a2_src = (const float*)d_in[7];
  const float* a2_dst = (const float*)d_in[8];
  const float* b2     = (const float*)d_in[9];
  const float* W3     = (const float*)d_in[10];
  const float* a3_src = (const float*)d_in[11];
  const float* a3_dst = (const float*)d_in[12];
  const float* b3     = (const float*)d_in[13];
  float* out = (float*)d_out;

  const int* esrc = ei;
  const int* edst = ei + ERAW;

  // Workspace carve-up. Ushort (bf16-split) buffers first (16B-aligned sizes).
  unsigned short* aHi  = (unsigned short*)d_ws;           // NN*WIDTH
  unsigned short* aLo  = aHi + (size_t)NN * WIDTH;
  unsigned short* w2tHi = aLo + (size_t)NN * WIDTH;       // 512*512
  unsigned short* w2tLo = w2tHi + (size_t)WIDTH * WIDTH;
  unsigned short* w3tHi = w2tLo + (size_t)WIDTH * WIDTH;  // 128*512
  unsigned short* w3tLo = w3tHi + (size_t)NCLS_P * WIDTH;
  float* bufA   = (float*)(w3tLo + (size_t)NCLS_P * WIDTH);  // NN*WIDTH
  float* bufB   = bufA + (size_t)NN * WIDTH;
  float* scores = bufB + (size_t)NN * WIDTH;              // ETOT*HEADS
  float* al_s   = scores + (size_t)ETOT * HEADS;
  float* al_d   = al_s + (size_t)NN * HEADS;
  unsigned* m_ord = (unsigned*)(al_d + (size_t)NN * HEADS);
  float* z      = (float*)m_ord + (size_t)NN * HEADS;
  int* deg      = (int*)(z + (size_t)NN * HEADS);
  int* rowptr   = deg + NN;
  int* cnt      = rowptr + NN + 4;
  int* ceid     = cnt + NN;
  int* csrc     = ceid + ETOT;

  // ---- build CSR by destination (once) ----
  hipMemsetAsync(deg, 0, (size_t)NN * sizeof(int), stream);
  hipMemsetAsync(cnt, 0, (size_t)NN * sizeof(int), stream);
  const int eblk = (ETOT + 255) / 256;
  count_deg<<<eblk, 256, 0, stream>>>(edst, deg);
  scan_deg<<<1, 256, 0, stream>>>(deg, rowptr);
  scatter_csr<<<eblk, 256, 0, stream>>>(esrc, edst, rowptr, cnt, ceid, csrc);

  // ---- weight transpose+split (once) ----
  transpose_split<<<dim3(WIDTH / 32, WIDTH / 32), 256, 0, stream>>>(
      W2, w2tHi, w2tLo, WIDTH, WIDTH, WIDTH);
  transpose_split<<<dim3(WIDTH / 32, NCLS_P / 32), 256, 0, stream>>>(
      W3, w3tHi, w3tLo, WIDTH, NCLS, NCLS_P);

  const int nwblk = (NN + 3) / 4;
  const int splitblk = ((NN * WIDTH / 4) + 255) / 256;

  // ---- Layer 1: x[20000,50] @ W1 -> h1(bufA); softmax-agg+ELU -> bufB ----
  {
    const int H = HEADS, C = HID;
    dim3 g((WIDTH + BN - 1) / BN, (NN + BM - 1) / BM);
    gemm_f32<<<g, 256, 0, stream>>>(x, W1, bufA, NN, F_IN, WIDTH);
    compute_al<<<nwblk, 256, 0, stream>>>(bufA, a1_src, a1_dst, al_s, al_d,
                                          NN, H, C);
    hipMemsetAsync(m_ord, 0, (size_t)NN * H * sizeof(unsigned), stream);
    hipMemsetAsync(z, 0, (size_t)NN * H * sizeof(float), stream);
    int tot = ETOT * H, blk = (tot + 255) / 256;
    edge_score_max<<<blk, 256, 0, stream>>>(esrc, edst, al_s, al_d, scores,
                                            m_ord, ETOT, ERAW, H);
    edge_exp_sum<<<blk, 256, 0, stream>>>(esrc, edst, scores, m_ord, z,
                                          ETOT, ERAW, H);
    pull_agg<HEADS, HID, true><<<nwblk, 256, 0, stream>>>(
        rowptr, ceid, csrc, scores, z, bufA, b1, bufB);
  }
  // ---- Layer 2: bufB @ W2 -> h2(bufA) via split-bf16 MFMA ----
  {
    const int H = 1, C = WIDTH;
    split_hi_lo4<<<splitblk, 256, 0, stream>>>((const float4*)bufB,
                                               (ushort4*)aHi, (ushort4*)aLo,
                                               NN * WIDTH / 4);
    gemm_mfma_split<<<dim3(WIDTH / 128, (NN + 127) / 128), 256, 0, stream>>>(
        aHi, aLo, w2tHi, w2tLo, bufA, NN, WIDTH, WIDTH);
    compute_al<<<nwblk, 256, 0, stream>>>(bufA, a2_src, a2_dst, al_s, al_d,
                                          NN, H, C);
    hipMemsetAsync(m_ord, 0, (size_t)NN * H * sizeof(unsigned), stream);
    hipMemsetAsync(z, 0, (size_t)NN * H * sizeof(float), stream);
    int tot = ETOT * H, blk = (tot + 255) / 256;
    edge_score_max<<<blk, 256, 0, stream>>>(esrc, edst, al_s, al_d, scores,
                                            m_ord, ETOT, ERAW, H);
    edge_exp_sum<<<blk, 256, 0, stream>>>(esrc, edst, scores, m_ord, z,
                                          ETOT, ERAW, H);
    pull_agg<1, WIDTH, true><<<nwblk, 256, 0, stream>>>(
        rowptr, ceid, csrc, scores, z, bufA, b2, bufB);
  }
  // ---- Layer 3: bufB @ W3 -> h3(bufA) via split-bf16 MFMA; agg -> out ----
  {
    const int H = 1, C = NCLS;
    split_hi_lo4<<<splitblk, 256, 0, stream>>>((const float4*)bufB,
                                               (ushort4*)aHi, (ushort4*)aLo,
                                               NN * WIDTH / 4);
    gemm_mfma_split<<<dim3(NCLS_P / 128, (NN + 127) / 128), 256, 0, stream>>>(
        aHi, aLo, w3tHi, w3tLo, bufA, NN, WIDTH, NCLS);
    compute_al<<<nwblk, 256, 0, stream>>>(bufA, a3_src, a3_dst, al_s, al_d,
                                          NN, H, C);
    hipMemsetAsync(m_ord, 0, (size_t)NN * H * sizeof(unsigned), stream);
    hipMemsetAsync(z, 0, (size_t)NN * H * sizeof(float), stream);
    int tot = ETOT * H, blk = (tot + 255) / 256;
    edge_score_max<<<blk, 256, 0, stream>>>(esrc, edst, al_s, al_d, scores,
                                            m_ord, ETOT, ERAW, H);
    edge_exp_sum<<<blk, 256, 0, stream>>>(esrc, edst, scores, m_ord, z,
                                          ETOT, ERAW, H);
    pull_agg<1, NCLS, false><<<nwblk, 256, 0, stream>>>(
        rowptr, ceid, csrc, scores, z, bufA, b3, out);
  }
}